// Round 1
// baseline (373.699 us; speedup 1.0000x reference)
//
#include <hip/hip_runtime.h>
#include <stdint.h>

#define NN 8192
#define K_ORD 262144u      // ordered top-k positions
#define K_PAIRS 131072u    // unordered pairs (each appears twice)
#define TIE_CAP 16384u

// ws layout (uint32 words):
// [0..2047]     hist1 (top 11 key bits)
// [2048..4095]  hist2 (next 11 key bits, within selected class)
// [4096..4111]  state: +0 done1, +1 done2, +2 selA, +3 aboveA(pairs),
//               +4 cls22, +5 r_ord, +6 tie_count
// [4112.. ]     tie buffer: uint2 {key, flat_idx}
#define ST 4096
#define ZERO_WORDS 4112

__device__ __forceinline__ uint32_t fkey(float x) {
    // order-preserving map float -> uint32 (neg: ~u, pos: u|0x80000000)
    uint32_t u = __float_as_uint(x);
    uint32_t m = (uint32_t)((int32_t)u >> 31) | 0x80000000u;
    return u ^ m;
}

__global__ void zero_ws_kernel(uint32_t* __restrict__ ws) {
    uint32_t t = blockIdx.x * blockDim.x + threadIdx.x;
    if (t < ZERO_WORDS) ws[t] = 0u;
}

// Triangular scan over pairs (i<j): histogram 11 bits of the product key.
// PASS 1: bits [31:21].  PASS 2: bits [20:10] filtered to top-11 == selA.
// Last-finishing block picks the threshold bucket on-device (no host sync).
template <int PASS>
__global__ void __launch_bounds__(256) scan_hist_kernel(const float* __restrict__ p,
                                                        uint32_t* __restrict__ ws) {
    __shared__ uint32_t lh[4 * 2056];   // 4 sub-histograms, stride 2056 (bank offset 8)
    __shared__ float pis[32];
    __shared__ uint32_t sdata[256];
    __shared__ uint32_t last_flag;

    uint32_t* hist_g = ws + (PASS == 1 ? 0 : 2048);
    const int tx = threadIdx.x;
    const int j0 = blockIdx.x * 1024;   // j tile (1024 wide)
    const int i0 = blockIdx.y * 32;     // i tile (32 rows)
    const bool active = (j0 + 1023) > i0;  // any j>i in tile?
    uint32_t selA = (PASS == 2) ? ws[ST + 2] : 0u;

    if (active) {
        for (int t = tx; t < 4 * 2056; t += 256) lh[t] = 0u;
        if (tx < 32) pis[tx] = p[i0 + tx];
        __syncthreads();

        const float4 pj = reinterpret_cast<const float4*>(p + j0)[tx];
        const int jb = j0 + tx * 4;
        uint32_t* myh = lh + (tx & 3) * 2056;

        for (int ii = 0; ii < 32; ++ii) {
            const int i = i0 + ii;
            const float pi = pis[ii];
            const uint32_t k0 = fkey(pi * pj.x);
            const uint32_t k1 = fkey(pi * pj.y);
            const uint32_t k2 = fkey(pi * pj.z);
            const uint32_t k3 = fkey(pi * pj.w);
            if (PASS == 1) {
                if (jb + 0 > i) atomicAdd(&myh[k0 >> 21], 1u);
                if (jb + 1 > i) atomicAdd(&myh[k1 >> 21], 1u);
                if (jb + 2 > i) atomicAdd(&myh[k2 >> 21], 1u);
                if (jb + 3 > i) atomicAdd(&myh[k3 >> 21], 1u);
            } else {
                if (jb + 0 > i && (k0 >> 21) == selA) atomicAdd(&myh[(k0 >> 10) & 0x7FFu], 1u);
                if (jb + 1 > i && (k1 >> 21) == selA) atomicAdd(&myh[(k1 >> 10) & 0x7FFu], 1u);
                if (jb + 2 > i && (k2 >> 21) == selA) atomicAdd(&myh[(k2 >> 10) & 0x7FFu], 1u);
                if (jb + 3 > i && (k3 >> 21) == selA) atomicAdd(&myh[(k3 >> 10) & 0x7FFu], 1u);
            }
        }
        __syncthreads();
        for (int b = tx; b < 2048; b += 256) {
            const uint32_t s = lh[b] + lh[2056 + b] + lh[2 * 2056 + b] + lh[3 * 2056 + b];
            if (s) atomicAdd(&hist_g[b], s);
        }
    }

    // ---- last-block election (all blocks, incl. inactive, participate) ----
    __syncthreads();   // implies vmcnt(0) drain: our flush atomics are at L2 (device-coherent)
    if (tx == 0) {
        __threadfence();
        const uint32_t old = atomicAdd(&ws[ST + (PASS - 1)], 1u);
        last_flag = (old == gridDim.x * gridDim.y - 1) ? 1u : 0u;
    }
    __syncthreads();
    if (!last_flag) return;

    // ---- pick phase: find bucket b with suffix(b) < Keff <= suffix(b)+h[b] ----
    uint32_t h[8];
    uint32_t cs = 0u;
#pragma unroll
    for (int q = 0; q < 8; ++q) {
        h[q] = __hip_atomic_load(&hist_g[tx * 8 + q], __ATOMIC_RELAXED, __HIP_MEMORY_SCOPE_AGENT);
        cs += h[q];
    }
    sdata[tx] = cs;
    __syncthreads();
    for (int off = 1; off < 256; off <<= 1) {   // Hillis-Steele inclusive suffix sum
        const uint32_t v = (tx + off < 256) ? sdata[tx + off] : 0u;
        __syncthreads();
        sdata[tx] += v;
        __syncthreads();
    }
    const uint32_t excl = sdata[tx] - cs;       // pairs in chunks strictly above mine

    const uint32_t aboveA = (PASS == 2) ? ws[ST + 3] : 0u;
    const uint32_t Keff = (PASS == 1) ? K_PAIRS : (K_PAIRS - aboveA);

    uint32_t run = excl;
#pragma unroll
    for (int q = 7; q >= 0; --q) {
        const uint32_t b = (uint32_t)(tx * 8 + q);
        const uint32_t cnt = h[q];
        if (run < Keff && Keff <= run + cnt) {   // unique bucket
            if (PASS == 1) {
                ws[ST + 2] = b;        // selA
                ws[ST + 3] = run;      // pairs strictly above class selA
            } else {
                const uint32_t above22 = aboveA + run;
                ws[ST + 4] = (selA << 11) | b;          // cls22 (key >> 10)
                ws[ST + 5] = K_ORD - 2u * above22;      // ordered slots inside class
            }
        }
        run += cnt;
    }
}

// Streamed 268MB mask write: 1.0 iff product key class > cls22; diag 0.
// In-class entries (the threshold's 1024-ulp neighborhood, ~tens) go to the tie buffer.
__global__ void __launch_bounds__(256) mask_kernel(const float* __restrict__ p,
                                                   float* __restrict__ out,
                                                   uint32_t* __restrict__ ws) {
    const int tx = threadIdx.x;
    const int i = blockIdx.y;
    const int jb0 = blockIdx.x * 4096;
    const uint32_t cls22 = ws[ST + 4];
    const float pi = p[i];
    uint2* tiebuf = reinterpret_cast<uint2*>(ws + ZERO_WORDS);
    const size_t rowbase = (size_t)i * NN;
#pragma unroll
    for (int q = 0; q < 4; ++q) {
        const int j = jb0 + q * 1024 + tx * 4;
        const float4 pj = *reinterpret_cast<const float4*>(p + j);
        const float pjv[4] = {pj.x, pj.y, pj.z, pj.w};
        float vv[4];
#pragma unroll
        for (int c = 0; c < 4; ++c) {
            const int jj = j + c;
            float v = 0.0f;
            if (jj != i) {
                const uint32_t key = fkey(pi * pjv[c]);
                const uint32_t cls = key >> 10;
                if (cls > cls22) {
                    v = 1.0f;
                } else if (cls == cls22) {
                    const uint32_t pos = atomicAdd(&ws[ST + 6], 1u);
                    if (pos < TIE_CAP) tiebuf[pos] = make_uint2(key, (uint32_t)(i * NN + jj));
                }
            }
            vv[c] = v;
        }
        float4 o;
        o.x = vv[0]; o.y = vv[1]; o.z = vv[2]; o.w = vv[3];
        *reinterpret_cast<float4*>(out + rowbase + j) = o;
    }
}

// Exact boundary resolution: top-r in-class entries by (key desc, flat idx asc),
// matching jax.lax.top_k tie semantics. M is tiny (~2x pairs in a 1024-ulp class).
__global__ void __launch_bounds__(256) tie_select_kernel(float* __restrict__ out,
                                                         uint32_t* __restrict__ ws) {
    uint32_t n = ws[ST + 6];
    if (n > TIE_CAP) n = TIE_CAP;
    const uint32_t r = ws[ST + 5];
    const uint2* buf = reinterpret_cast<const uint2*>(ws + ZERO_WORDS);
    for (uint32_t e = threadIdx.x; e < n; e += 256) {
        const uint2 me = buf[e];
        uint32_t rank = 0;
        for (uint32_t m = 0; m < n; ++m) {
            const uint2 o = buf[m];
            rank += ((o.x > me.x) || (o.x == me.x && o.y < me.y)) ? 1u : 0u;
        }
        if (rank < r) out[me.y] = 1.0f;
    }
}

extern "C" void kernel_launch(void* const* d_in, const int* in_sizes, int n_in,
                              void* d_out, int out_size, void* d_ws, size_t ws_size,
                              hipStream_t stream) {
    const float* p = (const float*)d_in[0];
    float* out = (float*)d_out;
    uint32_t* ws = (uint32_t*)d_ws;

    zero_ws_kernel<<<(ZERO_WORDS + 255) / 256, 256, 0, stream>>>(ws);

    const dim3 sg(8, 256);   // j-tiles x i-tiles, 2048 blocks, ~56% active (triangular)
    scan_hist_kernel<1><<<sg, 256, 0, stream>>>(p, ws);
    scan_hist_kernel<2><<<sg, 256, 0, stream>>>(p, ws);

    mask_kernel<<<dim3(2, NN), 256, 0, stream>>>(p, out, ws);
    tie_select_kernel<<<1, 256, 0, stream>>>(out, ws);
}

// Round 3
// 365.624 us; speedup vs baseline: 1.0221x; 1.0221x over previous
//
#include <hip/hip_runtime.h>
#include <stdint.h>

#define NN 8192
#define K_ORD 262144u      // ordered top-k positions (off-diagonal, both triangles)
#define TIE_CAP 16384u

// ws layout (uint32 words):
// [0..1023]    counts: round r (1..4) writes [ (r-1)*256 .. +255 ]
// [1024] Tk   [1025] above   [1026] r_ord   [1027] tie_cnt
// [1028..9219] sorted p values (8192 floats, descending by key)
// [9220..9220+TIE_CAP) tie flat-indices
#define WS_TK 1024
#define WS_ABOVE 1025
#define WS_R 1026
#define WS_TIECNT 1027
#define WS_SORT 1028
#define WS_TIE 9220

__device__ __forceinline__ uint32_t fkey(float x) {
    // order-preserving map float -> uint32 (neg: ~u, pos: u|0x80000000)
    uint32_t u = __float_as_uint(x);
    uint32_t m = (uint32_t)((int32_t)u >> 31) | 0x80000000u;
    return u ^ m;
}
__device__ __forceinline__ float inv_fkey(uint32_t k) {
    uint32_t u = (k & 0x80000000u) ? (k ^ 0x80000000u) : ~k;
    return __uint_as_float(u);
}

// ---------------------------------------------------------------------------
// Kernel 1: brute-force rank sort of p (desc by key, ties by index) -> ws sorted.
// 1024 blocks x 256 thr; block handles 8 elements; thread = (elem, 32-seg).
// LDS reads are stride-32 interleaved => bank-conflict-free (lane seg -> bank seg).
__global__ void __launch_bounds__(256) sort_kernel(const float* __restrict__ p,
                                                   uint32_t* __restrict__ ws) {
    __shared__ uint32_t ks[NN];
    const int tx = threadIdx.x;
    if (blockIdx.x == 0 && tx == 0) ws[WS_TIECNT] = 0u;  // mask's tie counter
    for (int t = tx; t < NN / 4; t += 256) {
        const float4 v = reinterpret_cast<const float4*>(p)[t];
        reinterpret_cast<uint4*>(ks)[t] =
            make_uint4(fkey(v.x), fkey(v.y), fkey(v.z), fkey(v.w));
    }
    __syncthreads();
    const int e = blockIdx.x * 8 + (tx >> 5);
    const int seg = tx & 31;
    const uint32_t ke = ks[e];
    uint32_t cnt = 0;
    for (int it = 0; it < 256; ++it) {
        const int j = seg + 32 * it;
        const uint32_t kj = ks[j];
        cnt += (kj > ke) ? 1u : 0u;
        cnt += (kj == ke && j < e) ? 1u : 0u;
    }
    for (int off = 16; off > 0; off >>= 1) cnt += __shfl_down(cnt, off, 32);
    if (seg == 0)
        reinterpret_cast<float*>(ws + WS_SORT)[cnt] = inv_fkey(ke);  // unique rank
}

// ---------------------------------------------------------------------------
// f(T) = #{ordered (a,b), a!=b : fkey(ps[a]*ps[b]) > T}, ps sorted desc by key.
// Per a: predicate is prefix-true (pa sign+) or suffix-true (pa sign-):
// one 14-step binary search each (search space [0,8192] -> first step NN!).
// NT threads cover 8192 a's.
template <int NT>
__device__ uint32_t eval_count(const float* __restrict__ ps, uint32_t T) {
    const int tx = threadIdx.x;
    const int apt = NN / NT;
    uint32_t cnt = 0;
    for (int q = 0; q < apt; ++q) {
        const int a = tx * apt + q;
        const float pa = ps[a];
        const uint32_t neg = __float_as_uint(pa) >> 31;
        int pos = 0;
#pragma unroll
        for (int st = NN; st > 0; st >>= 1) {   // st=8192 first: pos can reach 8192
            const int cand = pos + st;
            if (cand <= NN) {
                const uint32_t kk = fkey(pa * ps[cand - 1]);
                const uint32_t pr = (kk > T) ? 1u : 0u;
                if (pr ^ neg) pos = cand;
            }
        }
        uint32_t c = neg ? (uint32_t)(NN - pos) : (uint32_t)pos;
        c -= (fkey(pa * pa) > T) ? 1u : 0u;   // exclude the diagonal pairing
        cnt += c;
    }
    return cnt;
}

// Recompute the bracket after `rounds` completed rounds. Invariant:
// T* (minimal T with f(T) < K) lies in [lo, hi], f(hi) < K. Deterministic.
template <int NT>
__device__ void bracket_chain(const uint32_t* __restrict__ ws, int rounds,
                              uint32_t* sh, uint32_t& lo, uint32_t& hi,
                              uint32_t& fstar) {
    const int tx = threadIdx.x;
    lo = 0u; hi = 0xFFFFFFFFu; fstar = 0u;
    for (int r = 0; r < rounds; ++r) {
        uint32_t flag = 1024u;
        if (tx < 256 && ws[r * 256 + tx] < K_ORD) flag = (uint32_t)tx;
        sh[tx] = flag;
        __syncthreads();
        for (int off = NT / 2; off > 0; off >>= 1) {
            if (tx < off) sh[tx] = min(sh[tx], sh[tx + off]);
            __syncthreads();
        }
        const uint32_t cs = sh[0];   // minimal c with f(T_c) < K (exists: f(hi)<K)
        __syncthreads();
        fstar = ws[r * 256 + cs];
        const uint64_t W = (uint64_t)(hi - lo);
        const uint32_t Tc = lo + (uint32_t)(((uint64_t)(cs + 1) * W) >> 8);
        if (cs > 0) lo = lo + (uint32_t)(((uint64_t)cs * W) >> 8) + 1u;
        hi = Tc;
    }
}

// Kernels 2-5: one round of base-256 descent. Block c evaluates probe c.
template <int ROUND>
__global__ void __launch_bounds__(512) select_round_kernel(uint32_t* __restrict__ ws) {
    __shared__ float ps[NN];
    __shared__ uint32_t sh[512];
    const int tx = threadIdx.x;
    for (int t = tx; t < NN / 4; t += 512)
        reinterpret_cast<float4*>(ps)[t] =
            reinterpret_cast<const float4*>(ws + WS_SORT)[t];
    __syncthreads();
    uint32_t lo, hi, fs;
    bracket_chain<512>(ws, ROUND - 1, sh, lo, hi, fs);
    const uint64_t W = (uint64_t)(hi - lo);
    const uint32_t T = lo + (uint32_t)(((uint64_t)(blockIdx.x + 1) * W) >> 8);
    const uint32_t cnt = eval_count<512>(ps, T);
    __syncthreads();
    sh[tx] = cnt;
    __syncthreads();
    for (int off = 256; off > 0; off >>= 1) {
        if (tx < off) sh[tx] += sh[tx + off];
        __syncthreads();
    }
    if (tx == 0) ws[(ROUND - 1) * 256 + blockIdx.x] = sh[0];
}

// Kernel 6: after 4 rounds the bracket is a single key. Publish Tk/above/r.
__global__ void __launch_bounds__(256) finalize_kernel(uint32_t* __restrict__ ws) {
    __shared__ uint32_t sh[256];
    uint32_t lo, hi, fs;
    bracket_chain<256>(ws, 4, sh, lo, hi, fs);
    if (threadIdx.x == 0) {
        ws[WS_TK] = hi;               // == lo == exact K-th largest key
        ws[WS_ABOVE] = fs;            // f(Tk): strictly-greater count
        ws[WS_R] = K_ORD - fs;        // in-class slots, filled by index asc
    }
}

// Kernel 7: streamed 268MB mask write. 1.0 iff key > Tk; key == Tk -> tie buffer.
__global__ void __launch_bounds__(256) mask_kernel(const float* __restrict__ p,
                                                   float* __restrict__ out,
                                                   uint32_t* __restrict__ ws) {
    const int tx = threadIdx.x;
    const int i = blockIdx.y;
    const int jb0 = blockIdx.x * 4096;
    const uint32_t Tk = ws[WS_TK];
    const float pi = p[i];
    const size_t rowbase = (size_t)i * NN;
#pragma unroll
    for (int q = 0; q < 4; ++q) {
        const int j = jb0 + q * 1024 + tx * 4;
        const float4 pj = *reinterpret_cast<const float4*>(p + j);
        const float pjv[4] = {pj.x, pj.y, pj.z, pj.w};
        float vv[4];
#pragma unroll
        for (int c = 0; c < 4; ++c) {
            const int jj = j + c;
            float v = 0.0f;
            if (jj != i) {
                const uint32_t key = fkey(pi * pjv[c]);
                if (key > Tk) {
                    v = 1.0f;
                } else if (key == Tk) {
                    const uint32_t pos = atomicAdd(&ws[WS_TIECNT], 1u);
                    if (pos < TIE_CAP) ws[WS_TIE + pos] = (uint32_t)(i * NN + jj);
                }
            }
            vv[c] = v;
        }
        float4 o;
        o.x = vv[0]; o.y = vv[1]; o.z = vv[2]; o.w = vv[3];
        *reinterpret_cast<float4*>(out + rowbase + j) = o;
    }
}

// Kernel 8: among the n == #(key == Tk) entries, set the r with smallest flat
// index to 1.0 — exactly jax.lax.top_k's tie rule. n is tiny (usually 2).
__global__ void __launch_bounds__(256) tie_select_kernel(float* __restrict__ out,
                                                         uint32_t* __restrict__ ws) {
    uint32_t n = ws[WS_TIECNT];
    if (n > TIE_CAP) n = TIE_CAP;
    const uint32_t r = ws[WS_R];
    for (uint32_t e = threadIdx.x; e < n; e += 256) {
        const uint32_t idx = ws[WS_TIE + e];
        uint32_t rank = 0;
        for (uint32_t m = 0; m < n; ++m) rank += (ws[WS_TIE + m] < idx) ? 1u : 0u;
        if (rank < r) out[idx] = 1.0f;
    }
}

extern "C" void kernel_launch(void* const* d_in, const int* in_sizes, int n_in,
                              void* d_out, int out_size, void* d_ws, size_t ws_size,
                              hipStream_t stream) {
    const float* p = (const float*)d_in[0];
    float* out = (float*)d_out;
    uint32_t* ws = (uint32_t*)d_ws;

    sort_kernel<<<1024, 256, 0, stream>>>(p, ws);
    select_round_kernel<1><<<256, 512, 0, stream>>>(ws);
    select_round_kernel<2><<<256, 512, 0, stream>>>(ws);
    select_round_kernel<3><<<256, 512, 0, stream>>>(ws);
    select_round_kernel<4><<<256, 512, 0, stream>>>(ws);
    finalize_kernel<<<1, 256, 0, stream>>>(ws);
    mask_kernel<<<dim3(2, NN), 256, 0, stream>>>(p, out, ws);
    tie_select_kernel<<<1, 256, 0, stream>>>(out, ws);
}